// Round 1
// 640.721 us; speedup vs baseline: 2.4329x; 2.4329x over previous
//
#include <hip/hip_runtime.h>
#include <cstdint>
#include <cstddef>

#define BB 4
#define CIN 256
#define HH 128
#define WW 128
#define NANCH (HH*WW*9)    // 147456
#define PRE_K 600
#define POST_K 100
#define NMS_T 0.7f

typedef _Float16 f16x8 __attribute__((ext_vector_type(8)));
typedef float    f32x4 __attribute__((ext_vector_type(4)));

// ws layout (float units)
#define WS_SCORES 0                               // f32 [BB*NANCH]
#define WS_DELTAS (BB*NANCH)                      // f32 [BB*NANCH*4]
#define WS_BOXES  (WS_DELTAS + BB*NANCH*4)        // f32 [BB*PRE_K*4]
#define WS_TOPI   (WS_BOXES + BB*PRE_K*4)         // u32 [BB*PRE_K]
#define WS_WHI    (WS_TOPI + BB*PRE_K)            // fp16 [9][256][256] = 294912 floats
#define WS_WLO    (WS_WHI + 9*256*128)
#define WS_TOTAL  (WS_WLO + 9*256*128)

// ---------------------------------------------------------------------------
// Kernel 0: split conv weights (f32, scaled x64) into hi/lo fp16, layout
// [tap][oc][ic] so the conv kernel's A-tile staging is a contiguous slab.
// ---------------------------------------------------------------------------
__global__ void split_w(const float* __restrict__ convw,
                        _Float16* __restrict__ whi, _Float16* __restrict__ wlo)
{
    const int g = blockIdx.x * 256 + threadIdx.x;   // g = oc*256 + ic, 65536 total
    if (g >= 65536) return;
    #pragma unroll
    for (int t = 0; t < 9; ++t) {
        const float v = convw[(size_t)g*9 + t] * 64.f;
        const _Float16 h = (_Float16)v;
        const _Float16 lo = (_Float16)(v - (float)h);
        const size_t o = (size_t)t*65536 + g;
        whi[o] = h;
        wlo[o] = lo;
    }
}

// ---------------------------------------------------------------------------
// Kernel 1: 3x3 conv 256ic->256oc via MFMA f16 hi/lo split (3-term fp32 emu)
// + bias + ReLU + fused 1x1 heads, all per-block (no atomics).
// Block: 256 thr / 4 waves. Tile: 256 oc x 64 px (8x8 spatial).
// Per-wave: 64 oc x 64 px = 4x4 fragments of mfma_f32_16x16x32_f16.
// K-loop: 8 ic-chunks x 9 taps; halo (10x10x32ic) staged once per chunk.
// Scale: feat x16, weights x64 => acc = 1024*(conv); epilogue /1024 exact.
// ---------------------------------------------------------------------------
__global__ __launch_bounds__(256, 3)
void conv_mfma(const float* __restrict__ feat, const float* __restrict__ convb,
               const _Float16* __restrict__ whi, const _Float16* __restrict__ wlo,
               const float* __restrict__ clsw, const float* __restrict__ bboxw,
               float* __restrict__ scores, float* __restrict__ deltas)
{
    __shared__ __align__(16) unsigned char smem[46592];
    char* sAhi = (char*)smem;                 // [256 oc][32 ic] fp16, 16 KB
    char* sAlo = (char*)smem + 16384;         // 16 KB
    char* sHhi = (char*)smem + 32768;         // [100 rc][32 ic] fp16, 6.25 KB
    char* sHlo = (char*)smem + 39168;
    float* sBias = (float*)(smem + 45568);    // 1 KB

    const int bid = blockIdx.x;               // 1024 = b(4) x ty(16) x tx(16)
    const int b  = bid >> 8;
    const int ty = (bid >> 4) & 15;
    const int tx = bid & 15;
    const int tid = threadIdx.x;
    const int wm = tid >> 6;                  // wave id = oc quadrant
    const int l  = tid & 63;
    const int q  = l >> 4;                    // lane k-group
    const int c  = l & 15;                    // lane row/col within fragment

    const float* featb = feat + (size_t)b*CIN*HH*WW;

    // bias (pre-scaled by 1024) -> acc init
    sBias[tid] = convb[tid] * 1024.f;
    __syncthreads();
    f32x4 acc[4][4];
    #pragma unroll
    for (int mf = 0; mf < 4; ++mf) {
        const f32x4 bv = *(const f32x4*)(sBias + (wm*64 + mf*16 + 4*q));
        #pragma unroll
        for (int nf = 0; nf < 4; ++nf) acc[mf][nf] = bv;
    }

    for (int chunk = 0; chunk < 8; ++chunk) {
        const int ic0 = chunk*32;
        for (int t = 0; t < 9; ++t) {
            __syncthreads();
            // ---- stage A tile [256 oc][32 ic] hi+lo, XOR-swizzled slots ----
            {
                const size_t wbase = (size_t)t*65536 + ic0;
                #pragma unroll
                for (int j = 0; j < 4; ++j) {
                    const int idx = j*256 + tid;             // 0..1023
                    const int oc = idx >> 2, qq = idx & 3;
                    const size_t go = wbase + (size_t)oc*256 + qq*8;
                    const float4 vh = *(const float4*)(const void*)(whi + go);
                    const float4 vl = *(const float4*)(const void*)(wlo + go);
                    const int wb = oc*64 + ((qq ^ (oc & 3)) << 4);
                    *(float4*)(sAhi + wb) = vh;
                    *(float4*)(sAlo + wb) = vl;
                }
            }
            // ---- stage halo once per chunk: f32 -> (hi,lo) fp16, scaled x16
            if (t == 0) {
                for (int e = tid; e < 4096; e += 256) {
                    const int icl = e >> 7, s = e & 127;
                    if (s < 100) {
                        const int Y = s / 10, X = s - Y*10;
                        const int gy = ty*8 - 1 + Y, gx = tx*8 - 1 + X;
                        float v = 0.f;
                        if ((unsigned)gy < 128u && (unsigned)gx < 128u)
                            v = featb[((size_t)(ic0+icl)*HH + gy)*WW + gx];
                        v *= 16.f;
                        const _Float16 h = (_Float16)v;
                        const _Float16 lo = (_Float16)(v - (float)h);
                        const int base = s*64 + (((icl >> 3) ^ (X & 3)) << 4) + (icl & 7)*2;
                        *(_Float16*)(sHhi + base) = h;
                        *(_Float16*)(sHlo + base) = lo;
                    }
                }
            }
            __syncthreads();
            // ---- compute: 48 MFMA per wave per (tap,chunk) ----
            const int ky = t / 3, kx = t - ky*3;
            f16x8 bh[4], bl[4];
            #pragma unroll
            for (int nf = 0; nf < 4; ++nf) {
                const int py = nf*2 + (c >> 3);
                const int px = c & 7;
                const int X = px + kx;
                const int R = (py + ky)*10 + X;
                const int addr = R*64 + ((q ^ (X & 3)) << 4);
                bh[nf] = *(const f16x8*)(sHhi + addr);
                bl[nf] = *(const f16x8*)(sHlo + addr);
            }
            #pragma unroll
            for (int mf = 0; mf < 4; ++mf) {
                const int oc = wm*64 + mf*16 + c;
                const int aaddr = oc*64 + ((q ^ (oc & 3)) << 4);
                const f16x8 ah = *(const f16x8*)(sAhi + aaddr);
                const f16x8 al = *(const f16x8*)(sAlo + aaddr);
                #pragma unroll
                for (int nf = 0; nf < 4; ++nf) {
                    acc[mf][nf] = __builtin_amdgcn_mfma_f32_16x16x32_f16(ah, bh[nf], acc[mf][nf], 0, 0, 0);
                    acc[mf][nf] = __builtin_amdgcn_mfma_f32_16x16x32_f16(ah, bl[nf], acc[mf][nf], 0, 0, 0);
                    acc[mf][nf] = __builtin_amdgcn_mfma_f32_16x16x32_f16(al, bh[nf], acc[mf][nf], 0, 0, 0);
                }
            }
        }
    }

    // ---- epilogue: t = relu(acc)/1024 in place, then head fold ----
    #pragma unroll
    for (int mf = 0; mf < 4; ++mf)
        #pragma unroll
        for (int nf = 0; nf < 4; ++nf)
            #pragma unroll
            for (int r = 0; r < 4; ++r)
                acc[mf][nf][r] = fmaxf(acc[mf][nf][r], 0.f) * 0.0009765625f;

    float* sW15  = (float*)smem;              // [15][256] f32 (reuses A region)
    float* sPart = (float*)(smem + 16384);    // [4 wm][15][64 px] f32

    for (int g = 0; g < 3; ++g) {
        __syncthreads();
        // stage 15 head-weight rows (f32, full precision)
        for (int e = tid; e < 3840; e += 256) {
            const int chl = e >> 8, o = e & 255;
            const int ch = g*15 + chl;
            sW15[e] = (ch < 9) ? clsw[ch*256 + o] : bboxw[(ch - 9)*256 + o];
        }
        __syncthreads();
        // per-wave partial over its 64 oc, reduce over q via shfl
        for (int chl = 0; chl < 15; ++chl) {
            f32x4 wv[4];
            #pragma unroll
            for (int mf = 0; mf < 4; ++mf)
                wv[mf] = *(const f32x4*)(sW15 + chl*256 + wm*64 + mf*16 + 4*q);
            float p[4];
            #pragma unroll
            for (int nf = 0; nf < 4; ++nf) {
                float s = 0.f;
                #pragma unroll
                for (int mf = 0; mf < 4; ++mf)
                    #pragma unroll
                    for (int r = 0; r < 4; ++r)
                        s += wv[mf][r] * acc[mf][nf][r];
                s += __shfl_xor(s, 16, 64);
                s += __shfl_xor(s, 32, 64);
                p[nf] = s;
            }
            const float val = (q == 0) ? p[0] : (q == 1) ? p[1] : (q == 2) ? p[2] : p[3];
            sPart[(wm*15 + chl)*64 + q*16 + c] = val;
        }
        __syncthreads();
        // cross-wave reduce + global write (deterministic, no atomics)
        for (int e = tid; e < 960; e += 256) {
            const int chl = e >> 6, px = e & 63;
            const float s = sPart[chl*64 + px] + sPart[chl*64 + px + 960]
                          + sPart[chl*64 + px + 1920] + sPart[chl*64 + px + 2880];
            const int ch = g*15 + chl;
            const int gy = ty*8 + (px >> 3), gx = tx*8 + (px & 7);
            const int n4 = gy*WW + gx;
            if (ch < 9) scores[(size_t)b*NANCH + n4*9 + ch] = s;
            else {
                const int cc = ch - 9;
                deltas[((size_t)b*NANCH + n4*9 + (cc >> 2))*4 + (cc & 3)] = s;
            }
        }
    }
}

// ---------------------------------------------------------------------------
// Kernel 2: exact top-600 per image (radix threshold + deterministic sort).
// ---------------------------------------------------------------------------
__device__ inline unsigned score_key(float f) {
    unsigned u = __float_as_uint(f);
    return (u & 0x80000000u) ? ~u : (u | 0x80000000u);
}

__device__ inline void find_thresh(const unsigned* hist, int NB, unsigned target, unsigned* shv)
{
    const int tid = threadIdx.x;
    if (tid < 64) {
        const int gsz = NB >> 5;                  // 64 or 32
        unsigned gsum = 0;
        if (tid < 32)
            for (int k = 0; k < gsz; ++k)
                gsum += hist[tid*gsz + ((k + tid) & (gsz-1))];
        unsigned suf = gsum;
        #pragma unroll
        for (int d = 1; d < 32; d <<= 1) {
            const unsigned t = __shfl_down(suf, d, 64);
            if (tid + d < 32) suf += t;
        }
        const unsigned long long m = __ballot(tid < 32 && suf >= target);
        const int G = 63 - __clzll(m);
        unsigned caboveG = 0;
        { const unsigned t = __shfl(suf, G+1, 64); if (G < 31) caboveG = t; }
        unsigned h = 0;
        if (tid < gsz) h = hist[G*gsz + tid];
        unsigned wsuf = h;
        #pragma unroll
        for (int d = 1; d < 64; d <<= 1) {
            const unsigned t = __shfl_down(wsuf, d, 64);
            if (tid + d < gsz) wsuf += t;
        }
        const unsigned long long m2 = __ballot(tid < gsz && (caboveG + wsuf) >= target);
        const int L = 63 - __clzll(m2);
        if (tid == L) { shv[0] = (unsigned)(G*gsz + L); shv[1] = caboveG + wsuf - h; }
    }
}

__global__ __launch_bounds__(1024)
void topk_kernel(const float* __restrict__ scores, const float* __restrict__ clsb,
                 unsigned* __restrict__ topi)
{
    __shared__ unsigned hist[2048];
    __shared__ unsigned long long arr[1024];
    __shared__ unsigned tiebuf[1024];
    __shared__ float s_cb[9];
    __shared__ unsigned shv[8];
    const int b = blockIdx.x, tid = threadIdx.x;
    const float* si = scores + (size_t)b*NANCH;
    if (tid < 9) s_cb[tid] = clsb[tid];

    // pass A: top 11 bits
    for (int i = tid; i < 2048; i += 1024) hist[i] = 0;
    __syncthreads();
    for (int i = tid; i < NANCH; i += 1024) {
        const float sc = si[i] + s_cb[i % 9];
        atomicAdd(&hist[score_key(sc) >> 21], 1u);
    }
    __syncthreads();
    find_thresh(hist, 2048, PRE_K, shv);
    __syncthreads();
    const unsigned T1 = shv[0], gtA = shv[1];
    __syncthreads();

    // pass B: mid 11 bits
    for (int i = tid; i < 2048; i += 1024) hist[i] = 0;
    __syncthreads();
    for (int i = tid; i < NANCH; i += 1024) {
        const float sc = si[i] + s_cb[i % 9];
        const unsigned u = score_key(sc);
        if ((u >> 21) == T1) atomicAdd(&hist[(u >> 10) & 0x7FFu], 1u);
    }
    __syncthreads();
    find_thresh(hist, 2048, PRE_K - gtA, shv);
    __syncthreads();
    const unsigned T2 = shv[0], gtB = shv[1];
    const unsigned top22 = (T1 << 11) | T2;
    __syncthreads();

    // pass C: low 10 bits
    for (int i = tid; i < 1024; i += 1024) hist[i] = 0;
    __syncthreads();
    for (int i = tid; i < NANCH; i += 1024) {
        const float sc = si[i] + s_cb[i % 9];
        const unsigned u = score_key(sc);
        if ((u >> 10) == top22) atomicAdd(&hist[u & 0x3FFu], 1u);
    }
    __syncthreads();
    find_thresh(hist, 1024, PRE_K - gtA - gtB, shv);
    if (tid == 0) { shv[4] = 0; shv[5] = 0; }
    __syncthreads();
    const unsigned u_thr = (top22 << 10) | shv[0];
    const unsigned n_greater = gtA + gtB + shv[1];
    __syncthreads();

    // compact strictly-greater; collect ties
    for (int i = tid; i < NANCH; i += 1024) {
        const float sc = si[i] + s_cb[i % 9];
        const unsigned u = score_key(sc);
        if (u > u_thr) {
            const unsigned p = atomicAdd(&shv[4], 1u);
            arr[p] = ((unsigned long long)(~u) << 32) | (unsigned)i;
        } else if (u == u_thr) {
            const unsigned p = atomicAdd(&shv[5], 1u);
            if (p < 1024u) tiebuf[p] = (unsigned)i;
        }
    }
    __syncthreads();
    const unsigned cnt_tie = (shv[5] > 1024u) ? 1024u : shv[5];
    if ((unsigned)tid >= cnt_tie) tiebuf[tid] = 0xFFFFFFFFu;

    for (unsigned k = 2; k <= 1024; k <<= 1)
        for (unsigned j = k >> 1; j > 0; j >>= 1) {
            __syncthreads();
            const unsigned i = (unsigned)tid, ixj = i ^ j;
            if (ixj > i) {
                const unsigned a = tiebuf[i], cc = tiebuf[ixj];
                if ((a > cc) == ((i & k) == 0)) { tiebuf[i] = cc; tiebuf[ixj] = a; }
            }
        }
    __syncthreads();
    const unsigned ties_needed = PRE_K - n_greater;
    if ((unsigned)tid < ties_needed)
        arr[n_greater + tid] = ((unsigned long long)(~u_thr) << 32) | tiebuf[tid];
    if (tid >= PRE_K) arr[tid] = ~0ull;

    for (unsigned k = 2; k <= 1024; k <<= 1)
        for (unsigned j = k >> 1; j > 0; j >>= 1) {
            __syncthreads();
            const unsigned i = (unsigned)tid, ixj = i ^ j;
            if (ixj > i) {
                const unsigned long long a = arr[i], cc = arr[ixj];
                if ((a > cc) == ((i & k) == 0)) { arr[i] = cc; arr[ixj] = a; }
            }
        }
    __syncthreads();
    if (tid < PRE_K) topi[b*PRE_K + tid] = (unsigned)arr[tid];
}

// ---------------------------------------------------------------------------
// Kernel 3: decode + clip the 600 selected boxes per image.
// ---------------------------------------------------------------------------
__global__ void decode_kernel(const float* __restrict__ deltas,
                              const float* __restrict__ bboxb,
                              const unsigned* __restrict__ topi,
                              const int* __restrict__ imh, const int* __restrict__ imw,
                              float* __restrict__ boxes)
{
    const int g = blockIdx.x * blockDim.x + threadIdx.x;
    if (g >= BB * PRE_K) return;
    const int b = g / PRE_K;
    const int k = g - b * PRE_K;
    const unsigned idx = topi[b*PRE_K + k];
    const int a   = (int)(idx % 9u);
    const int n4  = (int)(idx / 9u);
    const int hh_ = n4 >> 7;
    const int ww_ = n4 & 127;
    const int si = a / 3, ri = a % 3;
    const double sq = (ri == 0) ? 0.70710678118654752440 : ((ri == 1) ? 1.0 : 1.41421356237309504880);
    const double sc = (si == 0) ? 8.0 : ((si == 1) ? 16.0 : 32.0);
    const float half_w = (float)(16.0 * sc * sq * 0.5);
    const float half_h = (float)(16.0 * sc / sq * 0.5);
    const float shx = 16.f * (float)ww_;
    const float shy = 16.f * (float)hh_;
    const float x1a = shx - half_w, x2a = shx + half_w;
    const float y1a = shy - half_h, y2a = shy + half_h;
    const float aw = x2a - x1a, ah = y2a - y1a;
    const float acx = x1a + 0.5f*aw, acy = y1a + 0.5f*ah;
    const float* d = deltas + ((size_t)b*NANCH + idx) * 4;
    const float dx = d[0] + bboxb[a*4+0];
    const float dy = d[1] + bboxb[a*4+1];
    const float dw = d[2] + bboxb[a*4+2];
    const float dh = d[3] + bboxb[a*4+3];
    const float pcx = acx + dx*aw;
    const float pcy = acy + dy*ah;
    const float pw  = aw * expf(dw);
    const float ph  = ah * expf(dh);
    const float fw = (float)imw[0], fh = (float)imh[0];
    float* o = boxes + (size_t)g * 4;
    o[0] = fminf(fmaxf(pcx - 0.5f*pw, 0.f), fw);
    o[1] = fminf(fmaxf(pcy - 0.5f*ph, 0.f), fh);
    o[2] = fminf(fmaxf(pcx + 0.5f*pw, 0.f), fw);
    o[3] = fminf(fmaxf(pcy + 0.5f*ph, 0.f), fh);
}

// ---------------------------------------------------------------------------
// Kernel 4: NMS + keep-ordered top-100 write.
// ---------------------------------------------------------------------------
__device__ inline unsigned long long shfl_u64(unsigned long long v, int src) {
    const int lo = __shfl((int)(v & 0xffffffffull), src, 64);
    const int hi = __shfl((int)(v >> 32), src, 64);
    return ((unsigned long long)(unsigned)hi << 32) | (unsigned)lo;
}

__global__ __launch_bounds__(1024)
void nms_kernel(const float* __restrict__ boxes, float* __restrict__ out)
{
    __shared__ float bx[PRE_K][4];
    __shared__ unsigned long long mrow[PRE_K][10];
    __shared__ unsigned long long keepw[10];
    __shared__ unsigned wpfx[11];
    __shared__ int sel[POST_K];
    const int b = blockIdx.x;
    const int tid = threadIdx.x;

    for (int e = tid; e < PRE_K*4; e += 1024)
        bx[e >> 2][e & 3] = boxes[(size_t)b*PRE_K*4 + e];
    __syncthreads();

    for (int item = tid; item < PRE_K*10; item += 1024) {
        const int i  = item / 10;
        const int wj = item - i*10;
        unsigned long long m = 0ull;
        const int jbase = wj * 64;
        if (jbase + 63 > i) {
            const float xi1 = bx[i][0], yi1 = bx[i][1], xi2 = bx[i][2], yi2 = bx[i][3];
            const float ai = (xi2 - xi1) * (yi2 - yi1);
            for (int bit = 0; bit < 64; ++bit) {
                const int j = jbase + bit;
                if (j < PRE_K && j > i) {
                    const float xx1 = fmaxf(xi1, bx[j][0]);
                    const float yy1 = fmaxf(yi1, bx[j][1]);
                    const float xx2 = fminf(xi2, bx[j][2]);
                    const float yy2 = fminf(yi2, bx[j][3]);
                    const float inter = fmaxf(xx2 - xx1, 0.f) * fmaxf(yy2 - yy1, 0.f);
                    const float aj = (bx[j][2] - bx[j][0]) * (bx[j][3] - bx[j][1]);
                    const float iou = inter / (ai + aj - inter);
                    if (iou > NMS_T) m |= (1ull << bit);
                }
            }
        }
        mrow[i][wj] = m;
    }
    __syncthreads();

    if (tid < 64) {
        const int lane = tid;
        unsigned long long kwv;
        if (lane < 9)       kwv = ~0ull;
        else if (lane == 9) kwv = (1ull << (PRE_K - 576)) - 1;
        else                kwv = 0ull;
        for (int w = 0; w < 10; ++w) {
            const int base = w*64;
            const int nb = (w == 9) ? (PRE_K - 576) : 64;
            if (lane == w) {
                for (int bit = 0; bit < nb; ++bit) {
                    const unsigned long long mm = mrow[base + bit][w];
                    if ((kwv >> bit) & 1ull) kwv &= ~mm;
                }
            }
            const unsigned long long fw = shfl_u64(kwv, w);
            if (lane > w && lane < 10) {
                for (int bit = 0; bit < nb; ++bit) {
                    const unsigned long long mm = mrow[base + bit][lane];
                    if ((fw >> bit) & 1ull) kwv &= ~mm;
                }
            }
        }
        if (lane < 10) keepw[lane] = kwv;
    }
    __syncthreads();
    if (tid == 0) {
        unsigned ccount = 0;
        #pragma unroll
        for (int w = 0; w < 10; ++w) { wpfx[w] = ccount; ccount += (unsigned)__popcll(keepw[w]); }
        wpfx[10] = ccount;
    }
    if (tid < POST_K) sel[tid] = -1;
    __syncthreads();
    if (tid < PRE_K) {
        const int w = tid >> 6, bit = tid & 63;
        const unsigned long long kw = keepw[w];
        if ((kw >> bit) & 1ull) {
            const unsigned rank = wpfx[w] + (unsigned)__popcll(kw & ((1ull << bit) - 1ull));
            if (rank < POST_K) sel[rank] = tid;
        }
    }
    __syncthreads();
    if (tid < POST_K) {
        const int s_ = sel[tid];
        float o0 = 0.f, o1 = 0.f, o2 = 0.f, o3 = 0.f;
        if (s_ >= 0) { o0 = bx[s_][0]; o1 = bx[s_][1]; o2 = bx[s_][2]; o3 = bx[s_][3]; }
        float* o = out + (size_t)b*POST_K*4 + tid*4;
        o[0] = o0; o[1] = o1; o[2] = o2; o[3] = o3;
    }
}

// ---------------------------------------------------------------------------
extern "C" void kernel_launch(void* const* d_in, const int* in_sizes, int n_in,
                              void* d_out, int out_size, void* d_ws, size_t ws_size,
                              hipStream_t stream) {
    const float* feat  = (const float*)d_in[0];
    const float* convw = (const float*)d_in[1];
    const float* convb = (const float*)d_in[2];
    const float* clsw  = (const float*)d_in[3];
    const float* clsb  = (const float*)d_in[4];
    const float* bboxw = (const float*)d_in[5];
    const float* bboxb = (const float*)d_in[6];
    const int*   imh   = (const int*)d_in[7];
    const int*   imw   = (const int*)d_in[8];

    if (ws_size < (size_t)WS_TOTAL * sizeof(float)) return;

    float*    scores = (float*)d_ws + WS_SCORES;
    float*    deltas = (float*)d_ws + WS_DELTAS;
    float*    boxes  = (float*)d_ws + WS_BOXES;
    unsigned* topi   = (unsigned*)((float*)d_ws + WS_TOPI);
    _Float16* whi    = (_Float16*)((float*)d_ws + WS_WHI);
    _Float16* wlo    = (_Float16*)((float*)d_ws + WS_WLO);
    float*    outp   = (float*)d_out;

    split_w<<<dim3(256), dim3(256), 0, stream>>>(convw, whi, wlo);
    conv_mfma<<<dim3(1024), dim3(256), 0, stream>>>(feat, convb, whi, wlo, clsw, bboxw,
                                                    scores, deltas);
    topk_kernel<<<dim3(BB), dim3(1024), 0, stream>>>(scores, clsb, topi);
    decode_kernel<<<dim3((BB*PRE_K + 255)/256), dim3(256), 0, stream>>>(deltas, bboxb, topi, imh, imw, boxes);
    nms_kernel<<<dim3(BB), dim3(1024), 0, stream>>>(boxes, outp);
}

// Round 2
// 612.210 us; speedup vs baseline: 2.5462x; 1.0466x over previous
//
#include <hip/hip_runtime.h>
#include <cstdint>
#include <cstddef>

#define BB 4
#define CIN 256
#define HH 128
#define WW 128
#define NANCH (HH*WW*9)    // 147456
#define PRE_K 600
#define POST_K 100
#define NMS_T 0.7f

typedef _Float16 f16x8 __attribute__((ext_vector_type(8)));
typedef float    f32x4 __attribute__((ext_vector_type(4)));

// ws layout (float units)
#define WS_SCORES 0                               // f32 [BB*NANCH]
#define WS_DELTAS (BB*NANCH)                      // f32 [BB*NANCH*4]
#define WS_BOXES  (WS_DELTAS + BB*NANCH*4)        // f32 [BB*PRE_K*4]
#define WS_TOPI   (WS_BOXES + BB*PRE_K*4)         // u32 [BB*PRE_K]
#define WS_WHI    (WS_TOPI + BB*PRE_K)            // fp16 [9][8][256][32]
#define WS_WLO    (WS_WHI + 9*256*128)
#define WS_TOTAL  (WS_WLO + 9*256*128)

// ---------------------------------------------------------------------------
// Kernel 0: split conv weights (f32, scaled x64) into hi/lo fp16, layout
// [tap][ic_chunk][oc][icl] so a wave's MFMA A-fragment load is one fully
// coalesced 1KB global_load_dwordx4 burst (L2-resident, no LDS round trip).
// ---------------------------------------------------------------------------
__global__ void split_w(const float* __restrict__ convw,
                        _Float16* __restrict__ whi, _Float16* __restrict__ wlo)
{
    const int g = blockIdx.x * 256 + threadIdx.x;   // g = oc*256 + ic, 65536 total
    if (g >= 65536) return;
    const int oc = g >> 8, ic = g & 255;
    const int chunk = ic >> 5, icl = ic & 31;
    #pragma unroll
    for (int t = 0; t < 9; ++t) {
        const float v = convw[(size_t)g*9 + t] * 64.f;
        const _Float16 h = (_Float16)v;
        const _Float16 lo = (_Float16)(v - (float)h);
        const size_t o = (size_t)((t*8 + chunk)*256 + oc)*32 + icl;
        whi[o] = h;
        wlo[o] = lo;
    }
}

// ---------------------------------------------------------------------------
// Kernel 1: 3x3 conv 256ic->256oc via MFMA f16 hi/lo split (3-term fp32 emu)
// + bias + ReLU + fused 1x1 heads, all per-block (no atomics).
// Block: 256 thr / 4 waves; tile 256 oc x 64 px (8x8 spatial).
// A (weights) read DIRECTLY from global (L2-hot) in fragment layout -> no
// A-LDS staging, no per-tap barriers. B (halo) double-buffered in LDS with a
// conflict-free XOR swizzle; ONE barrier per 32-ic chunk.
// Scale: feat x16, weights x64 => acc = 1024*(conv); epilogue /1024 exact.
// ---------------------------------------------------------------------------
__global__ __launch_bounds__(256, 3)
void conv_mfma(const float* __restrict__ feat, const float* __restrict__ convb,
               const _Float16* __restrict__ whi, const _Float16* __restrict__ wlo,
               const float* __restrict__ clsw, const float* __restrict__ bboxw,
               float* __restrict__ scores, float* __restrict__ deltas)
{
    // conv phase: halo hi[2] @0/6400, lo[2] @12800/19200; bias @25600 (1KB)
    // epilogue:   sW15 @0 (15360 B), sPart @15360 (15360 B)
    __shared__ __align__(16) unsigned char smem[30720];
    float* sBias = (float*)(smem + 25600);

    const int bid0 = blockIdx.x;                // 1024 blocks; XCD-swizzle (1024%8==0)
    const int bid  = (bid0 & 7) * 128 + (bid0 >> 3);
    const int b  = bid >> 8;
    const int ty = (bid >> 4) & 15;
    const int tx = bid & 15;
    const int h0 = ty*8, c0 = tx*8;
    const int tid = threadIdx.x;
    const int wm = tid >> 6;                    // wave id = oc quadrant
    const int l  = tid & 63;
    const int q  = l >> 4;                      // lane k-group
    const int c  = l & 15;                      // lane row/col within fragment

    const float* featb = feat + (size_t)b*CIN*HH*WW;
    // per-lane base offset into [oc][32ic] weight slab (f16 units)
    const int wOff = (wm*64 + c)*32 + q*8;

    // bias (pre-scaled by 1024) -> acc init
    sBias[tid] = convb[tid] * 1024.f;

    // halo staging: f32 -> (hi,lo) fp16, scaled x16, swizzled slots.
    // layout: s(=Y*10+X)*64B + ((icg ^ g)<<4) + (ic&7)*2, g = ((X>>1)&1)|((Y&1)<<1)
    auto stage = [&](int ck, int buf) {
        unsigned char* hb = smem + buf*6400;
        unsigned char* lb = smem + 12800 + buf*6400;
        const int ic0s = ck*32;
        for (int e = tid; e < 400; e += 256) {
            const int icg = e / 100, s = e - icg*100;
            const int Y = s / 10, X = s - Y*10;
            const int gy = h0 - 1 + Y, gx = c0 - 1 + X;
            const int g = ((X >> 1) & 1) | ((Y & 1) << 1);
            const bool inb = ((unsigned)gy < 128u) && ((unsigned)gx < 128u);
            f16x8 hv, lv;
            #pragma unroll
            for (int k = 0; k < 8; ++k) {
                float v = 0.f;
                if (inb) v = featb[((size_t)(ic0s + icg*8 + k)*HH + gy)*WW + gx];
                v *= 16.f;
                const _Float16 h = (_Float16)v;
                hv[k] = h;
                lv[k] = (_Float16)(v - (float)h);
            }
            const int base = s*64 + ((icg ^ g) << 4);
            *(f16x8*)(hb + base) = hv;
            *(f16x8*)(lb + base) = lv;
        }
    };

    stage(0, 0);
    __syncthreads();

    f32x4 acc[4][4];
    #pragma unroll
    for (int mf = 0; mf < 4; ++mf) {
        const f32x4 bv = *(const f32x4*)(sBias + (wm*64 + mf*16 + 4*q));
        #pragma unroll
        for (int nf = 0; nf < 4; ++nf) acc[mf][nf] = bv;
    }

    for (int chunk = 0; chunk < 8; ++chunk) {
        const int cur = chunk & 1;
        if (chunk + 1 < 8) stage(chunk + 1, cur ^ 1);   // overlaps with t-loop below
        const unsigned char* hb = smem + cur*6400;
        const unsigned char* lb = smem + 12800 + cur*6400;

        #pragma unroll 3
        for (int t = 0; t < 9; ++t) {
            const int ky = t / 3, kx = t - ky*3;
            // ---- A fragments: direct global loads (coalesced, L2-hot) ----
            const _Float16* pWh = whi + (size_t)(t*8 + chunk)*8192 + wOff;
            const _Float16* pWl = wlo + (size_t)(t*8 + chunk)*8192 + wOff;
            f16x8 ah[4], al[4];
            #pragma unroll
            for (int mf = 0; mf < 4; ++mf) {
                ah[mf] = *(const f16x8*)(const void*)(pWh + mf*512);
                al[mf] = *(const f16x8*)(const void*)(pWl + mf*512);
            }
            // ---- B fragments from swizzled halo LDS (conflict-free) ----
            f16x8 bh[4], bl[4];
            #pragma unroll
            for (int nf = 0; nf < 4; ++nf) {
                const int py = nf*2 + (c >> 3);
                const int X = (c & 7) + kx;
                const int Y = py + ky;
                const int g = ((X >> 1) & 1) | ((Y & 1) << 1);
                const int addr = (Y*10 + X)*64 + ((q ^ g) << 4);
                bh[nf] = *(const f16x8*)(hb + addr);
                bl[nf] = *(const f16x8*)(lb + addr);
            }
            // ---- 48 MFMA ----
            #pragma unroll
            for (int mf = 0; mf < 4; ++mf)
                #pragma unroll
                for (int nf = 0; nf < 4; ++nf) {
                    acc[mf][nf] = __builtin_amdgcn_mfma_f32_16x16x32_f16(ah[mf], bh[nf], acc[mf][nf], 0, 0, 0);
                    acc[mf][nf] = __builtin_amdgcn_mfma_f32_16x16x32_f16(ah[mf], bl[nf], acc[mf][nf], 0, 0, 0);
                    acc[mf][nf] = __builtin_amdgcn_mfma_f32_16x16x32_f16(al[mf], bh[nf], acc[mf][nf], 0, 0, 0);
                }
        }
        __syncthreads();   // halo buf cur^1 staged; buf cur reads done
    }

    // ---- epilogue: t = relu(acc)/1024 in place, then head fold ----
    #pragma unroll
    for (int mf = 0; mf < 4; ++mf)
        #pragma unroll
        for (int nf = 0; nf < 4; ++nf)
            #pragma unroll
            for (int r = 0; r < 4; ++r)
                acc[mf][nf][r] = fmaxf(acc[mf][nf][r], 0.f) * 0.0009765625f;

    float* sW15  = (float*)smem;              // [15][256] f32
    float* sPart = (float*)(smem + 15360);    // [4 wm][15][64 px] f32

    for (int g = 0; g < 3; ++g) {
        __syncthreads();
        for (int e = tid; e < 3840; e += 256) {
            const int chl = e >> 8, o = e & 255;
            const int ch = g*15 + chl;
            sW15[e] = (ch < 9) ? clsw[ch*256 + o] : bboxw[(ch - 9)*256 + o];
        }
        __syncthreads();
        for (int chl = 0; chl < 15; ++chl) {
            f32x4 wv[4];
            #pragma unroll
            for (int mf = 0; mf < 4; ++mf)
                wv[mf] = *(const f32x4*)(sW15 + chl*256 + wm*64 + mf*16 + 4*q);
            float p[4];
            #pragma unroll
            for (int nf = 0; nf < 4; ++nf) {
                float s = 0.f;
                #pragma unroll
                for (int mf = 0; mf < 4; ++mf)
                    #pragma unroll
                    for (int r = 0; r < 4; ++r)
                        s += wv[mf][r] * acc[mf][nf][r];
                s += __shfl_xor(s, 16, 64);
                s += __shfl_xor(s, 32, 64);
                p[nf] = s;
            }
            const float val = (q == 0) ? p[0] : (q == 1) ? p[1] : (q == 2) ? p[2] : p[3];
            sPart[(wm*15 + chl)*64 + q*16 + c] = val;
        }
        __syncthreads();
        for (int e = tid; e < 960; e += 256) {
            const int chl = e >> 6, px = e & 63;
            const float s = sPart[chl*64 + px] + sPart[chl*64 + px + 960]
                          + sPart[chl*64 + px + 1920] + sPart[chl*64 + px + 2880];
            const int ch = g*15 + chl;
            const int gy = h0 + (px >> 3), gx = c0 + (px & 7);
            const int n4 = gy*WW + gx;
            if (ch < 9) scores[(size_t)b*NANCH + n4*9 + ch] = s;
            else {
                const int cc = ch - 9;
                deltas[((size_t)b*NANCH + n4*9 + (cc >> 2))*4 + (cc & 3)] = s;
            }
        }
    }
}

// ---------------------------------------------------------------------------
// Kernel 2: exact top-600 per image (radix threshold + deterministic sort).
// ---------------------------------------------------------------------------
__device__ inline unsigned score_key(float f) {
    unsigned u = __float_as_uint(f);
    return (u & 0x80000000u) ? ~u : (u | 0x80000000u);
}

__device__ inline void find_thresh(const unsigned* hist, int NB, unsigned target, unsigned* shv)
{
    const int tid = threadIdx.x;
    if (tid < 64) {
        const int gsz = NB >> 5;                  // 64 or 32
        unsigned gsum = 0;
        if (tid < 32)
            for (int k = 0; k < gsz; ++k)
                gsum += hist[tid*gsz + ((k + tid) & (gsz-1))];
        unsigned suf = gsum;
        #pragma unroll
        for (int d = 1; d < 32; d <<= 1) {
            const unsigned t = __shfl_down(suf, d, 64);
            if (tid + d < 32) suf += t;
        }
        const unsigned long long m = __ballot(tid < 32 && suf >= target);
        const int G = 63 - __clzll(m);
        unsigned caboveG = 0;
        { const unsigned t = __shfl(suf, G+1, 64); if (G < 31) caboveG = t; }
        unsigned h = 0;
        if (tid < gsz) h = hist[G*gsz + tid];
        unsigned wsuf = h;
        #pragma unroll
        for (int d = 1; d < 64; d <<= 1) {
            const unsigned t = __shfl_down(wsuf, d, 64);
            if (tid + d < gsz) wsuf += t;
        }
        const unsigned long long m2 = __ballot(tid < gsz && (caboveG + wsuf) >= target);
        const int L = 63 - __clzll(m2);
        if (tid == L) { shv[0] = (unsigned)(G*gsz + L); shv[1] = caboveG + wsuf - h; }
    }
}

__global__ __launch_bounds__(1024)
void topk_kernel(const float* __restrict__ scores, const float* __restrict__ clsb,
                 unsigned* __restrict__ topi)
{
    __shared__ unsigned hist[2048];
    __shared__ unsigned long long arr[1024];
    __shared__ unsigned tiebuf[1024];
    __shared__ float s_cb[9];
    __shared__ unsigned shv[8];
    const int b = blockIdx.x, tid = threadIdx.x;
    const float* si = scores + (size_t)b*NANCH;
    if (tid < 9) s_cb[tid] = clsb[tid];

    // pass A: top 11 bits
    for (int i = tid; i < 2048; i += 1024) hist[i] = 0;
    __syncthreads();
    for (int i = tid; i < NANCH; i += 1024) {
        const float sc = si[i] + s_cb[i % 9];
        atomicAdd(&hist[score_key(sc) >> 21], 1u);
    }
    __syncthreads();
    find_thresh(hist, 2048, PRE_K, shv);
    __syncthreads();
    const unsigned T1 = shv[0], gtA = shv[1];
    __syncthreads();

    // pass B: mid 11 bits
    for (int i = tid; i < 2048; i += 1024) hist[i] = 0;
    __syncthreads();
    for (int i = tid; i < NANCH; i += 1024) {
        const float sc = si[i] + s_cb[i % 9];
        const unsigned u = score_key(sc);
        if ((u >> 21) == T1) atomicAdd(&hist[(u >> 10) & 0x7FFu], 1u);
    }
    __syncthreads();
    find_thresh(hist, 2048, PRE_K - gtA, shv);
    __syncthreads();
    const unsigned T2 = shv[0], gtB = shv[1];
    const unsigned top22 = (T1 << 11) | T2;
    __syncthreads();

    // pass C: low 10 bits
    for (int i = tid; i < 1024; i += 1024) hist[i] = 0;
    __syncthreads();
    for (int i = tid; i < NANCH; i += 1024) {
        const float sc = si[i] + s_cb[i % 9];
        const unsigned u = score_key(sc);
        if ((u >> 10) == top22) atomicAdd(&hist[u & 0x3FFu], 1u);
    }
    __syncthreads();
    find_thresh(hist, 1024, PRE_K - gtA - gtB, shv);
    if (tid == 0) { shv[4] = 0; shv[5] = 0; }
    __syncthreads();
    const unsigned u_thr = (top22 << 10) | shv[0];
    const unsigned n_greater = gtA + gtB + shv[1];
    __syncthreads();

    // compact strictly-greater; collect ties
    for (int i = tid; i < NANCH; i += 1024) {
        const float sc = si[i] + s_cb[i % 9];
        const unsigned u = score_key(sc);
        if (u > u_thr) {
            const unsigned p = atomicAdd(&shv[4], 1u);
            arr[p] = ((unsigned long long)(~u) << 32) | (unsigned)i;
        } else if (u == u_thr) {
            const unsigned p = atomicAdd(&shv[5], 1u);
            if (p < 1024u) tiebuf[p] = (unsigned)i;
        }
    }
    __syncthreads();
    const unsigned cnt_tie = (shv[5] > 1024u) ? 1024u : shv[5];
    if ((unsigned)tid >= cnt_tie) tiebuf[tid] = 0xFFFFFFFFu;

    for (unsigned k = 2; k <= 1024; k <<= 1)
        for (unsigned j = k >> 1; j > 0; j >>= 1) {
            __syncthreads();
            const unsigned i = (unsigned)tid, ixj = i ^ j;
            if (ixj > i) {
                const unsigned a = tiebuf[i], cc = tiebuf[ixj];
                if ((a > cc) == ((i & k) == 0)) { tiebuf[i] = cc; tiebuf[ixj] = a; }
            }
        }
    __syncthreads();
    const unsigned ties_needed = PRE_K - n_greater;
    if ((unsigned)tid < ties_needed)
        arr[n_greater + tid] = ((unsigned long long)(~u_thr) << 32) | tiebuf[tid];
    if (tid >= PRE_K) arr[tid] = ~0ull;

    for (unsigned k = 2; k <= 1024; k <<= 1)
        for (unsigned j = k >> 1; j > 0; j >>= 1) {
            __syncthreads();
            const unsigned i = (unsigned)tid, ixj = i ^ j;
            if (ixj > i) {
                const unsigned long long a = arr[i], cc = arr[ixj];
                if ((a > cc) == ((i & k) == 0)) { arr[i] = cc; arr[ixj] = a; }
            }
        }
    __syncthreads();
    if (tid < PRE_K) topi[b*PRE_K + tid] = (unsigned)arr[tid];
}

// ---------------------------------------------------------------------------
// Kernel 3: decode + clip the 600 selected boxes per image.
// ---------------------------------------------------------------------------
__global__ void decode_kernel(const float* __restrict__ deltas,
                              const float* __restrict__ bboxb,
                              const unsigned* __restrict__ topi,
                              const int* __restrict__ imh, const int* __restrict__ imw,
                              float* __restrict__ boxes)
{
    const int g = blockIdx.x * blockDim.x + threadIdx.x;
    if (g >= BB * PRE_K) return;
    const int b = g / PRE_K;
    const int k = g - b * PRE_K;
    const unsigned idx = topi[b*PRE_K + k];
    const int a   = (int)(idx % 9u);
    const int n4  = (int)(idx / 9u);
    const int hh_ = n4 >> 7;
    const int ww_ = n4 & 127;
    const int si = a / 3, ri = a % 3;
    const double sq = (ri == 0) ? 0.70710678118654752440 : ((ri == 1) ? 1.0 : 1.41421356237309504880);
    const double sc = (si == 0) ? 8.0 : ((si == 1) ? 16.0 : 32.0);
    const float half_w = (float)(16.0 * sc * sq * 0.5);
    const float half_h = (float)(16.0 * sc / sq * 0.5);
    const float shx = 16.f * (float)ww_;
    const float shy = 16.f * (float)hh_;
    const float x1a = shx - half_w, x2a = shx + half_w;
    const float y1a = shy - half_h, y2a = shy + half_h;
    const float aw = x2a - x1a, ah = y2a - y1a;
    const float acx = x1a + 0.5f*aw, acy = y1a + 0.5f*ah;
    const float* d = deltas + ((size_t)b*NANCH + idx) * 4;
    const float dx = d[0] + bboxb[a*4+0];
    const float dy = d[1] + bboxb[a*4+1];
    const float dw = d[2] + bboxb[a*4+2];
    const float dh = d[3] + bboxb[a*4+3];
    const float pcx = acx + dx*aw;
    const float pcy = acy + dy*ah;
    const float pw  = aw * expf(dw);
    const float ph  = ah * expf(dh);
    const float fw = (float)imw[0], fh = (float)imh[0];
    float* o = boxes + (size_t)g * 4;
    o[0] = fminf(fmaxf(pcx - 0.5f*pw, 0.f), fw);
    o[1] = fminf(fmaxf(pcy - 0.5f*ph, 0.f), fh);
    o[2] = fminf(fmaxf(pcx + 0.5f*pw, 0.f), fw);
    o[3] = fminf(fmaxf(pcy + 0.5f*ph, 0.f), fh);
}

// ---------------------------------------------------------------------------
// Kernel 4: NMS + keep-ordered top-100 write.
// ---------------------------------------------------------------------------
__device__ inline unsigned long long shfl_u64(unsigned long long v, int src) {
    const int lo = __shfl((int)(v & 0xffffffffull), src, 64);
    const int hi = __shfl((int)(v >> 32), src, 64);
    return ((unsigned long long)(unsigned)hi << 32) | (unsigned)lo;
}

__global__ __launch_bounds__(1024)
void nms_kernel(const float* __restrict__ boxes, float* __restrict__ out)
{
    __shared__ float bx[PRE_K][4];
    __shared__ unsigned long long mrow[PRE_K][10];
    __shared__ unsigned long long keepw[10];
    __shared__ unsigned wpfx[11];
    __shared__ int sel[POST_K];
    const int b = blockIdx.x;
    const int tid = threadIdx.x;

    for (int e = tid; e < PRE_K*4; e += 1024)
        bx[e >> 2][e & 3] = boxes[(size_t)b*PRE_K*4 + e];
    __syncthreads();

    for (int item = tid; item < PRE_K*10; item += 1024) {
        const int i  = item / 10;
        const int wj = item - i*10;
        unsigned long long m = 0ull;
        const int jbase = wj * 64;
        if (jbase + 63 > i) {
            const float xi1 = bx[i][0], yi1 = bx[i][1], xi2 = bx[i][2], yi2 = bx[i][3];
            const float ai = (xi2 - xi1) * (yi2 - yi1);
            for (int bit = 0; bit < 64; ++bit) {
                const int j = jbase + bit;
                if (j < PRE_K && j > i) {
                    const float xx1 = fmaxf(xi1, bx[j][0]);
                    const float yy1 = fmaxf(yi1, bx[j][1]);
                    const float xx2 = fminf(xi2, bx[j][2]);
                    const float yy2 = fminf(yi2, bx[j][3]);
                    const float inter = fmaxf(xx2 - xx1, 0.f) * fmaxf(yy2 - yy1, 0.f);
                    const float aj = (bx[j][2] - bx[j][0]) * (bx[j][3] - bx[j][1]);
                    const float iou = inter / (ai + aj - inter);
                    if (iou > NMS_T) m |= (1ull << bit);
                }
            }
        }
        mrow[i][wj] = m;
    }
    __syncthreads();

    if (tid < 64) {
        const int lane = tid;
        unsigned long long kwv;
        if (lane < 9)       kwv = ~0ull;
        else if (lane == 9) kwv = (1ull << (PRE_K - 576)) - 1;
        else                kwv = 0ull;
        for (int w = 0; w < 10; ++w) {
            const int base = w*64;
            const int nb = (w == 9) ? (PRE_K - 576) : 64;
            if (lane == w) {
                for (int bit = 0; bit < nb; ++bit) {
                    const unsigned long long mm = mrow[base + bit][w];
                    if ((kwv >> bit) & 1ull) kwv &= ~mm;
                }
            }
            const unsigned long long fw = shfl_u64(kwv, w);
            if (lane > w && lane < 10) {
                for (int bit = 0; bit < nb; ++bit) {
                    const unsigned long long mm = mrow[base + bit][lane];
                    if ((fw >> bit) & 1ull) kwv &= ~mm;
                }
            }
        }
        if (lane < 10) keepw[lane] = kwv;
    }
    __syncthreads();
    if (tid == 0) {
        unsigned ccount = 0;
        #pragma unroll
        for (int w = 0; w < 10; ++w) { wpfx[w] = ccount; ccount += (unsigned)__popcll(keepw[w]); }
        wpfx[10] = ccount;
    }
    if (tid < POST_K) sel[tid] = -1;
    __syncthreads();
    if (tid < PRE_K) {
        const int w = tid >> 6, bit = tid & 63;
        const unsigned long long kw = keepw[w];
        if ((kw >> bit) & 1ull) {
            const unsigned rank = wpfx[w] + (unsigned)__popcll(kw & ((1ull << bit) - 1ull));
            if (rank < POST_K) sel[rank] = tid;
        }
    }
    __syncthreads();
    if (tid < POST_K) {
        const int s_ = sel[tid];
        float o0 = 0.f, o1 = 0.f, o2 = 0.f, o3 = 0.f;
        if (s_ >= 0) { o0 = bx[s_][0]; o1 = bx[s_][1]; o2 = bx[s_][2]; o3 = bx[s_][3]; }
        float* o = out + (size_t)b*POST_K*4 + tid*4;
        o[0] = o0; o[1] = o1; o[2] = o2; o[3] = o3;
    }
}

// ---------------------------------------------------------------------------
extern "C" void kernel_launch(void* const* d_in, const int* in_sizes, int n_in,
                              void* d_out, int out_size, void* d_ws, size_t ws_size,
                              hipStream_t stream) {
    const float* feat  = (const float*)d_in[0];
    const float* convw = (const float*)d_in[1];
    const float* convb = (const float*)d_in[2];
    const float* clsw  = (const float*)d_in[3];
    const float* clsb  = (const float*)d_in[4];
    const float* bboxw = (const float*)d_in[5];
    const float* bboxb = (const float*)d_in[6];
    const int*   imh   = (const int*)d_in[7];
    const int*   imw   = (const int*)d_in[8];

    if (ws_size < (size_t)WS_TOTAL * sizeof(float)) return;

    float*    scores = (float*)d_ws + WS_SCORES;
    float*    deltas = (float*)d_ws + WS_DELTAS;
    float*    boxes  = (float*)d_ws + WS_BOXES;
    unsigned* topi   = (unsigned*)((float*)d_ws + WS_TOPI);
    _Float16* whi    = (_Float16*)((float*)d_ws + WS_WHI);
    _Float16* wlo    = (_Float16*)((float*)d_ws + WS_WLO);
    float*    outp   = (float*)d_out;

    split_w<<<dim3(256), dim3(256), 0, stream>>>(convw, whi, wlo);
    conv_mfma<<<dim3(1024), dim3(256), 0, stream>>>(feat, convb, whi, wlo, clsw, bboxw,
                                                    scores, deltas);
    topk_kernel<<<dim3(BB), dim3(1024), 0, stream>>>(scores, clsb, topi);
    decode_kernel<<<dim3((BB*PRE_K + 255)/256), dim3(256), 0, stream>>>(deltas, bboxb, topi, imh, imw, boxes);
    nms_kernel<<<dim3(BB), dim3(1024), 0, stream>>>(boxes, outp);
}

// Round 3
// 528.641 us; speedup vs baseline: 2.9487x; 1.1581x over previous
//
#include <hip/hip_runtime.h>
#include <cstdint>
#include <cstddef>

#define BB 4
#define CIN 256
#define HH 128
#define WW 128
#define NANCH (HH*WW*9)    // 147456
#define PRE_K 600
#define POST_K 100
#define NMS_T 0.7f

typedef _Float16 f16x8 __attribute__((ext_vector_type(8)));
typedef float    f32x4 __attribute__((ext_vector_type(4)));

// ws layout (float units)
#define WS_SCORES 0                               // f32 [BB*NANCH]
#define WS_DELTAS (BB*NANCH)                      // f32 [BB*NANCH*4]
#define WS_BOXES  (WS_DELTAS + BB*NANCH*4)        // f32 [BB*PRE_K*4]
#define WS_TOPI   (WS_BOXES + BB*PRE_K*4)         // u32 [BB*PRE_K]
#define WS_WHI    (WS_TOPI + BB*PRE_K)            // fp16 [9][8][256][32]
#define WS_WLO    (WS_WHI + 9*256*128)
#define WS_TOTAL  (WS_WLO + 9*256*128)

// ---------------------------------------------------------------------------
// Kernel 0: split conv weights (f32, scaled x64) into hi/lo fp16, layout
// [tap][ic_chunk][oc][icl] so a wave's MFMA A-fragment load is one fully
// coalesced 1KB global_load_dwordx4 burst (L2-resident, no LDS round trip).
// ---------------------------------------------------------------------------
__global__ void split_w(const float* __restrict__ convw,
                        _Float16* __restrict__ whi, _Float16* __restrict__ wlo)
{
    const int g = blockIdx.x * 256 + threadIdx.x;   // g = oc*256 + ic, 65536 total
    if (g >= 65536) return;
    const int oc = g >> 8, ic = g & 255;
    const int chunk = ic >> 5, icl = ic & 31;
    #pragma unroll
    for (int t = 0; t < 9; ++t) {
        const float v = convw[(size_t)g*9 + t] * 64.f;
        const _Float16 h = (_Float16)v;
        const _Float16 lo = (_Float16)(v - (float)h);
        const size_t o = (size_t)((t*8 + chunk)*256 + oc)*32 + icl;
        whi[o] = h;
        wlo[o] = lo;
    }
}

// ---------------------------------------------------------------------------
// Kernel 1: 3x3 conv 256ic->256oc via MFMA f16 hi/lo split (3-term fp32 emu)
// + bias + ReLU + fused 1x1 heads, all per-block (no atomics).
// Block: 512 thr / 8 waves; tile 256 oc x 256 px (16x16 spatial); grid 256
// (1 block/CU). Wave = 64 oc (wm quadrant) x 128 px (wph half): acc[4][8].
// A (weights) read DIRECTLY from global in fragment layout: per-phase working
// set is 32KB -> L2-resident; total A-traffic 1.15 GB (was 2.3 GB at 64 px).
// B (halo 18x18x32ic) double-buffered in LDS, conflict-free XOR swizzle;
// ONE barrier per 32-ic chunk.
// Scale: feat x16, weights x64 => acc = 1024*(conv); epilogue /1024 exact.
// ---------------------------------------------------------------------------
__global__ __launch_bounds__(512, 2)
void conv_mfma(const float* __restrict__ feat, const float* __restrict__ convb,
               const _Float16* __restrict__ whi, const _Float16* __restrict__ wlo,
               const float* __restrict__ clsw, const float* __restrict__ bboxw,
               float* __restrict__ scores, float* __restrict__ deltas)
{
    // conv phase: halo hi[2] @0/20736, lo[2] @41472/62208; bias @82944 (1KB)
    // epilogue:   sW15 @0 (15360 B), sPart @15360 (61440 B)
    __shared__ __align__(16) unsigned char smem[83968];
    float* sBias = (float*)(smem + 82944);

    const int bid = blockIdx.x;                 // 256 = b(4) x ty(8) x tx(8)
    const int b  = bid >> 6;
    const int ty = (bid >> 3) & 7;
    const int tx = bid & 7;
    const int h0 = ty*16, c0 = tx*16;
    const int tid = threadIdx.x;
    const int w   = tid >> 6;                   // wave 0..7
    const int wm  = w >> 1;                     // oc quadrant
    const int wph = w & 1;                      // px half (rows 0-7 / 8-15)
    const int l  = tid & 63;
    const int q  = l >> 4;                      // lane k-group
    const int c  = l & 15;                      // lane row/col within fragment

    const float* featb = feat + (size_t)b*CIN*HH*WW;
    // per-lane base offset into [oc][32ic] weight slab (f16 units)
    const int wOff = (wm*64 + c)*32 + q*8;

    // bias (pre-scaled by 1024) -> acc init
    if (tid < 256) sBias[tid] = convb[tid] * 1024.f;

    // halo staging: f32 -> (hi,lo) fp16, scaled x16, swizzled slots.
    // layout: s(=Y*18+X)*64B + ((icg ^ g)<<4), g = ((X>>1)&1)|((Y&1)<<1)
    auto stage = [&](int ck, int buf) {
        unsigned char* hb = smem + buf*20736;
        unsigned char* lb = smem + 41472 + buf*20736;
        const int ic0s = ck*32;
        for (int e = tid; e < 1296; e += 512) {
            const int icg = e / 324, s = e - icg*324;
            const int Y = s / 18, X = s - Y*18;
            const int gy = h0 - 1 + Y, gx = c0 - 1 + X;
            const int g = ((X >> 1) & 1) | ((Y & 1) << 1);
            const bool inb = ((unsigned)gy < 128u) && ((unsigned)gx < 128u);
            f16x8 hv, lv;
            #pragma unroll
            for (int k = 0; k < 8; ++k) {
                float v = 0.f;
                if (inb) v = featb[((size_t)(ic0s + icg*8 + k)*HH + gy)*WW + gx];
                v *= 16.f;
                const _Float16 h = (_Float16)v;
                hv[k] = h;
                lv[k] = (_Float16)(v - (float)h);
            }
            const int base = s*64 + ((icg ^ g) << 4);
            *(f16x8*)(hb + base) = hv;
            *(f16x8*)(lb + base) = lv;
        }
    };

    stage(0, 0);
    __syncthreads();

    f32x4 acc[4][8];
    #pragma unroll
    for (int mf = 0; mf < 4; ++mf) {
        const f32x4 bv = *(const f32x4*)(sBias + (wm*64 + mf*16 + 4*q));
        #pragma unroll
        for (int nf = 0; nf < 8; ++nf) acc[mf][nf] = bv;
    }

    for (int chunk = 0; chunk < 8; ++chunk) {
        const int cur = chunk & 1;
        if (chunk + 1 < 8) stage(chunk + 1, cur ^ 1);   // overlaps with t-loop
        const unsigned char* hb = smem + cur*20736;
        const unsigned char* lb = smem + 41472 + cur*20736;

        #pragma unroll 3
        for (int t = 0; t < 9; ++t) {
            const int ky = t / 3, kx = t - ky*3;
            // ---- A fragments: direct global loads (coalesced, L2-hot) ----
            const _Float16* pWh = whi + (size_t)(t*8 + chunk)*8192 + wOff;
            const _Float16* pWl = wlo + (size_t)(t*8 + chunk)*8192 + wOff;
            f16x8 ah[4], al[4];
            #pragma unroll
            for (int mf = 0; mf < 4; ++mf) {
                ah[mf] = *(const f16x8*)(const void*)(pWh + mf*512);
                al[mf] = *(const f16x8*)(const void*)(pWl + mf*512);
            }
            // ---- B fragments in two nf-halves (keeps VGPR pressure down) ----
            #pragma unroll
            for (int nfh = 0; nfh < 2; ++nfh) {
                f16x8 bh[4], bl[4];
                #pragma unroll
                for (int j = 0; j < 4; ++j) {
                    const int nf = nfh*4 + j;
                    const int Y = wph*8 + (nf >> 1)*2 + (c >> 3) + ky;
                    const int X = (nf & 1)*8 + (c & 7) + kx;
                    const int g = ((X >> 1) & 1) | ((Y & 1) << 1);
                    const int addr = (Y*18 + X)*64 + ((q ^ g) << 4);
                    bh[j] = *(const f16x8*)(hb + addr);
                    bl[j] = *(const f16x8*)(lb + addr);
                }
                #pragma unroll
                for (int mf = 0; mf < 4; ++mf)
                    #pragma unroll
                    for (int j = 0; j < 4; ++j) {
                        acc[mf][nfh*4+j] = __builtin_amdgcn_mfma_f32_16x16x32_f16(ah[mf], bh[j], acc[mf][nfh*4+j], 0, 0, 0);
                        acc[mf][nfh*4+j] = __builtin_amdgcn_mfma_f32_16x16x32_f16(ah[mf], bl[j], acc[mf][nfh*4+j], 0, 0, 0);
                        acc[mf][nfh*4+j] = __builtin_amdgcn_mfma_f32_16x16x32_f16(al[mf], bh[j], acc[mf][nfh*4+j], 0, 0, 0);
                    }
            }
        }
        __syncthreads();   // halo buf cur^1 staged; buf cur reads done
    }

    // ---- epilogue: t = relu(acc)/1024 in place, then head fold ----
    #pragma unroll
    for (int mf = 0; mf < 4; ++mf)
        #pragma unroll
        for (int nf = 0; nf < 8; ++nf)
            #pragma unroll
            for (int r = 0; r < 4; ++r)
                acc[mf][nf][r] = fmaxf(acc[mf][nf][r], 0.f) * 0.0009765625f;

    float* sW15  = (float*)smem;              // [15][256] f32
    float* sPart = (float*)(smem + 15360);    // [8 w][15][128 px] f32

    for (int g = 0; g < 3; ++g) {
        __syncthreads();
        for (int e = tid; e < 3840; e += 512) {
            const int chl = e >> 8, o = e & 255;
            const int ch = g*15 + chl;
            sW15[e] = (ch < 9) ? clsw[ch*256 + o] : bboxw[(ch - 9)*256 + o];
        }
        __syncthreads();
        for (int chl = 0; chl < 15; ++chl) {
            f32x4 wv[4];
            #pragma unroll
            for (int mf = 0; mf < 4; ++mf)
                wv[mf] = *(const f32x4*)(sW15 + chl*256 + wm*64 + mf*16 + 4*q);
            float p[8];
            #pragma unroll
            for (int nf = 0; nf < 8; ++nf) {
                float s = 0.f;
                #pragma unroll
                for (int mf = 0; mf < 4; ++mf)
                    #pragma unroll
                    for (int r = 0; r < 4; ++r)
                        s += wv[mf][r] * acc[mf][nf][r];
                s += __shfl_xor(s, 16, 64);
                s += __shfl_xor(s, 32, 64);
                p[nf] = s;
            }
            // lane (q,c) stores px fragments nf=q and nf=q+4 (fully q-reduced)
            const float v0 = (q == 0) ? p[0] : (q == 1) ? p[1] : (q == 2) ? p[2] : p[3];
            const float v1 = (q == 0) ? p[4] : (q == 1) ? p[5] : (q == 2) ? p[6] : p[7];
            sPart[(w*15 + chl)*128 + q*16 + c]      = v0;
            sPart[(w*15 + chl)*128 + 64 + q*16 + c] = v1;
        }
        __syncthreads();
        // cross-wave reduce over the 4 oc-quadrants (deterministic order)
        for (int e = tid; e < 3840; e += 512) {
            const int chl = e >> 8, pxg = e & 255;
            const int ph = pxg >> 7, pxl = pxg & 127;
            float s = 0.f;
            #pragma unroll
            for (int wmq = 0; wmq < 4; ++wmq)
                s += sPart[((wmq*2 + ph)*15 + chl)*128 + pxl];
            const int nf = pxl >> 4, cc2 = pxl & 15;
            const int Y = ph*8 + (nf >> 1)*2 + (cc2 >> 3);
            const int X = (nf & 1)*8 + (cc2 & 7);
            const int ch = g*15 + chl;
            const int gy = h0 + Y, gx = c0 + X;
            const int n4 = gy*WW + gx;
            if (ch < 9) scores[(size_t)b*NANCH + n4*9 + ch] = s;
            else {
                const int cc = ch - 9;
                deltas[((size_t)b*NANCH + n4*9 + (cc >> 2))*4 + (cc & 3)] = s;
            }
        }
    }
}

// ---------------------------------------------------------------------------
// Kernel 2: exact top-600 per image (radix threshold + deterministic sort).
// ---------------------------------------------------------------------------
__device__ inline unsigned score_key(float f) {
    unsigned u = __float_as_uint(f);
    return (u & 0x80000000u) ? ~u : (u | 0x80000000u);
}

__device__ inline void find_thresh(const unsigned* hist, int NB, unsigned target, unsigned* shv)
{
    const int tid = threadIdx.x;
    if (tid < 64) {
        const int gsz = NB >> 5;                  // 64 or 32
        unsigned gsum = 0;
        if (tid < 32)
            for (int k = 0; k < gsz; ++k)
                gsum += hist[tid*gsz + ((k + tid) & (gsz-1))];
        unsigned suf = gsum;
        #pragma unroll
        for (int d = 1; d < 32; d <<= 1) {
            const unsigned t = __shfl_down(suf, d, 64);
            if (tid + d < 32) suf += t;
        }
        const unsigned long long m = __ballot(tid < 32 && suf >= target);
        const int G = 63 - __clzll(m);
        unsigned caboveG = 0;
        { const unsigned t = __shfl(suf, G+1, 64); if (G < 31) caboveG = t; }
        unsigned h = 0;
        if (tid < gsz) h = hist[G*gsz + tid];
        unsigned wsuf = h;
        #pragma unroll
        for (int d = 1; d < 64; d <<= 1) {
            const unsigned t = __shfl_down(wsuf, d, 64);
            if (tid + d < gsz) wsuf += t;
        }
        const unsigned long long m2 = __ballot(tid < gsz && (caboveG + wsuf) >= target);
        const int L = 63 - __clzll(m2);
        if (tid == L) { shv[0] = (unsigned)(G*gsz + L); shv[1] = caboveG + wsuf - h; }
    }
}

__global__ __launch_bounds__(1024)
void topk_kernel(const float* __restrict__ scores, const float* __restrict__ clsb,
                 unsigned* __restrict__ topi)
{
    __shared__ unsigned hist[2048];
    __shared__ unsigned long long arr[1024];
    __shared__ unsigned tiebuf[1024];
    __shared__ float s_cb[9];
    __shared__ unsigned shv[8];
    const int b = blockIdx.x, tid = threadIdx.x;
    const float* si = scores + (size_t)b*NANCH;
    if (tid < 9) s_cb[tid] = clsb[tid];

    // pass A: top 11 bits
    for (int i = tid; i < 2048; i += 1024) hist[i] = 0;
    __syncthreads();
    for (int i = tid; i < NANCH; i += 1024) {
        const float sc = si[i] + s_cb[i % 9];
        atomicAdd(&hist[score_key(sc) >> 21], 1u);
    }
    __syncthreads();
    find_thresh(hist, 2048, PRE_K, shv);
    __syncthreads();
    const unsigned T1 = shv[0], gtA = shv[1];
    __syncthreads();

    // pass B: mid 11 bits
    for (int i = tid; i < 2048; i += 1024) hist[i] = 0;
    __syncthreads();
    for (int i = tid; i < NANCH; i += 1024) {
        const float sc = si[i] + s_cb[i % 9];
        const unsigned u = score_key(sc);
        if ((u >> 21) == T1) atomicAdd(&hist[(u >> 10) & 0x7FFu], 1u);
    }
    __syncthreads();
    find_thresh(hist, 2048, PRE_K - gtA, shv);
    __syncthreads();
    const unsigned T2 = shv[0], gtB = shv[1];
    const unsigned top22 = (T1 << 11) | T2;
    __syncthreads();

    // pass C: low 10 bits
    for (int i = tid; i < 1024; i += 1024) hist[i] = 0;
    __syncthreads();
    for (int i = tid; i < NANCH; i += 1024) {
        const float sc = si[i] + s_cb[i % 9];
        const unsigned u = score_key(sc);
        if ((u >> 10) == top22) atomicAdd(&hist[u & 0x3FFu], 1u);
    }
    __syncthreads();
    find_thresh(hist, 1024, PRE_K - gtA - gtB, shv);
    if (tid == 0) { shv[4] = 0; shv[5] = 0; }
    __syncthreads();
    const unsigned u_thr = (top22 << 10) | shv[0];
    const unsigned n_greater = gtA + gtB + shv[1];
    __syncthreads();

    // compact strictly-greater; collect ties
    for (int i = tid; i < NANCH; i += 1024) {
        const float sc = si[i] + s_cb[i % 9];
        const unsigned u = score_key(sc);
        if (u > u_thr) {
            const unsigned p = atomicAdd(&shv[4], 1u);
            arr[p] = ((unsigned long long)(~u) << 32) | (unsigned)i;
        } else if (u == u_thr) {
            const unsigned p = atomicAdd(&shv[5], 1u);
            if (p < 1024u) tiebuf[p] = (unsigned)i;
        }
    }
    __syncthreads();
    const unsigned cnt_tie = (shv[5] > 1024u) ? 1024u : shv[5];
    if ((unsigned)tid >= cnt_tie) tiebuf[tid] = 0xFFFFFFFFu;

    for (unsigned k = 2; k <= 1024; k <<= 1)
        for (unsigned j = k >> 1; j > 0; j >>= 1) {
            __syncthreads();
            const unsigned i = (unsigned)tid, ixj = i ^ j;
            if (ixj > i) {
                const unsigned a = tiebuf[i], cc = tiebuf[ixj];
                if ((a > cc) == ((i & k) == 0)) { tiebuf[i] = cc; tiebuf[ixj] = a; }
            }
        }
    __syncthreads();
    const unsigned ties_needed = PRE_K - n_greater;
    if ((unsigned)tid < ties_needed)
        arr[n_greater + tid] = ((unsigned long long)(~u_thr) << 32) | tiebuf[tid];
    if (tid >= PRE_K) arr[tid] = ~0ull;

    for (unsigned k = 2; k <= 1024; k <<= 1)
        for (unsigned j = k >> 1; j > 0; j >>= 1) {
            __syncthreads();
            const unsigned i = (unsigned)tid, ixj = i ^ j;
            if (ixj > i) {
                const unsigned long long a = arr[i], cc = arr[ixj];
                if ((a > cc) == ((i & k) == 0)) { arr[i] = cc; arr[ixj] = a; }
            }
        }
    __syncthreads();
    if (tid < PRE_K) topi[b*PRE_K + tid] = (unsigned)arr[tid];
}

// ---------------------------------------------------------------------------
// Kernel 3: decode + clip the 600 selected boxes per image.
// ---------------------------------------------------------------------------
__global__ void decode_kernel(const float* __restrict__ deltas,
                              const float* __restrict__ bboxb,
                              const unsigned* __restrict__ topi,
                              const int* __restrict__ imh, const int* __restrict__ imw,
                              float* __restrict__ boxes)
{
    const int g = blockIdx.x * blockDim.x + threadIdx.x;
    if (g >= BB * PRE_K) return;
    const int b = g / PRE_K;
    const int k = g - b * PRE_K;
    const unsigned idx = topi[b*PRE_K + k];
    const int a   = (int)(idx % 9u);
    const int n4  = (int)(idx / 9u);
    const int hh_ = n4 >> 7;
    const int ww_ = n4 & 127;
    const int si = a / 3, ri = a % 3;
    const double sq = (ri == 0) ? 0.70710678118654752440 : ((ri == 1) ? 1.0 : 1.41421356237309504880);
    const double sc = (si == 0) ? 8.0 : ((si == 1) ? 16.0 : 32.0);
    const float half_w = (float)(16.0 * sc * sq * 0.5);
    const float half_h = (float)(16.0 * sc / sq * 0.5);
    const float shx = 16.f * (float)ww_;
    const float shy = 16.f * (float)hh_;
    const float x1a = shx - half_w, x2a = shx + half_w;
    const float y1a = shy - half_h, y2a = shy + half_h;
    const float aw = x2a - x1a, ah = y2a - y1a;
    const float acx = x1a + 0.5f*aw, acy = y1a + 0.5f*ah;
    const float* d = deltas + ((size_t)b*NANCH + idx) * 4;
    const float dx = d[0] + bboxb[a*4+0];
    const float dy = d[1] + bboxb[a*4+1];
    const float dw = d[2] + bboxb[a*4+2];
    const float dh = d[3] + bboxb[a*4+3];
    const float pcx = acx + dx*aw;
    const float pcy = acy + dy*ah;
    const float pw  = aw * expf(dw);
    const float ph  = ah * expf(dh);
    const float fw = (float)imw[0], fh = (float)imh[0];
    float* o = boxes + (size_t)g * 4;
    o[0] = fminf(fmaxf(pcx - 0.5f*pw, 0.f), fw);
    o[1] = fminf(fmaxf(pcy - 0.5f*ph, 0.f), fh);
    o[2] = fminf(fmaxf(pcx + 0.5f*pw, 0.f), fw);
    o[3] = fminf(fmaxf(pcy + 0.5f*ph, 0.f), fh);
}

// ---------------------------------------------------------------------------
// Kernel 4: NMS + keep-ordered top-100 write.
// ---------------------------------------------------------------------------
__device__ inline unsigned long long shfl_u64(unsigned long long v, int src) {
    const int lo = __shfl((int)(v & 0xffffffffull), src, 64);
    const int hi = __shfl((int)(v >> 32), src, 64);
    return ((unsigned long long)(unsigned)hi << 32) | (unsigned)lo;
}

__global__ __launch_bounds__(1024)
void nms_kernel(const float* __restrict__ boxes, float* __restrict__ out)
{
    __shared__ float bx[PRE_K][4];
    __shared__ unsigned long long mrow[PRE_K][10];
    __shared__ unsigned long long keepw[10];
    __shared__ unsigned wpfx[11];
    __shared__ int sel[POST_K];
    const int b = blockIdx.x;
    const int tid = threadIdx.x;

    for (int e = tid; e < PRE_K*4; e += 1024)
        bx[e >> 2][e & 3] = boxes[(size_t)b*PRE_K*4 + e];
    __syncthreads();

    for (int item = tid; item < PRE_K*10; item += 1024) {
        const int i  = item / 10;
        const int wj = item - i*10;
        unsigned long long m = 0ull;
        const int jbase = wj * 64;
        if (jbase + 63 > i) {
            const float xi1 = bx[i][0], yi1 = bx[i][1], xi2 = bx[i][2], yi2 = bx[i][3];
            const float ai = (xi2 - xi1) * (yi2 - yi1);
            for (int bit = 0; bit < 64; ++bit) {
                const int j = jbase + bit;
                if (j < PRE_K && j > i) {
                    const float xx1 = fmaxf(xi1, bx[j][0]);
                    const float yy1 = fmaxf(yi1, bx[j][1]);
                    const float xx2 = fminf(xi2, bx[j][2]);
                    const float yy2 = fminf(yi2, bx[j][3]);
                    const float inter = fmaxf(xx2 - xx1, 0.f) * fmaxf(yy2 - yy1, 0.f);
                    const float aj = (bx[j][2] - bx[j][0]) * (bx[j][3] - bx[j][1]);
                    const float iou = inter / (ai + aj - inter);
                    if (iou > NMS_T) m |= (1ull << bit);
                }
            }
        }
        mrow[i][wj] = m;
    }
    __syncthreads();

    if (tid < 64) {
        const int lane = tid;
        unsigned long long kwv;
        if (lane < 9)       kwv = ~0ull;
        else if (lane == 9) kwv = (1ull << (PRE_K - 576)) - 1;
        else                kwv = 0ull;
        for (int w = 0; w < 10; ++w) {
            const int base = w*64;
            const int nb = (w == 9) ? (PRE_K - 576) : 64;
            if (lane == w) {
                for (int bit = 0; bit < nb; ++bit) {
                    const unsigned long long mm = mrow[base + bit][w];
                    if ((kwv >> bit) & 1ull) kwv &= ~mm;
                }
            }
            const unsigned long long fw = shfl_u64(kwv, w);
            if (lane > w && lane < 10) {
                for (int bit = 0; bit < nb; ++bit) {
                    const unsigned long long mm = mrow[base + bit][lane];
                    if ((fw >> bit) & 1ull) kwv &= ~mm;
                }
            }
        }
        if (lane < 10) keepw[lane] = kwv;
    }
    __syncthreads();
    if (tid == 0) {
        unsigned ccount = 0;
        #pragma unroll
        for (int w = 0; w < 10; ++w) { wpfx[w] = ccount; ccount += (unsigned)__popcll(keepw[w]); }
        wpfx[10] = ccount;
    }
    if (tid < POST_K) sel[tid] = -1;
    __syncthreads();
    if (tid < PRE_K) {
        const int w = tid >> 6, bit = tid & 63;
        const unsigned long long kw = keepw[w];
        if ((kw >> bit) & 1ull) {
            const unsigned rank = wpfx[w] + (unsigned)__popcll(kw & ((1ull << bit) - 1ull));
            if (rank < POST_K) sel[rank] = tid;
        }
    }
    __syncthreads();
    if (tid < POST_K) {
        const int s_ = sel[tid];
        float o0 = 0.f, o1 = 0.f, o2 = 0.f, o3 = 0.f;
        if (s_ >= 0) { o0 = bx[s_][0]; o1 = bx[s_][1]; o2 = bx[s_][2]; o3 = bx[s_][3]; }
        float* o = out + (size_t)b*POST_K*4 + tid*4;
        o[0] = o0; o[1] = o1; o[2] = o2; o[3] = o3;
    }
}

// ---------------------------------------------------------------------------
extern "C" void kernel_launch(void* const* d_in, const int* in_sizes, int n_in,
                              void* d_out, int out_size, void* d_ws, size_t ws_size,
                              hipStream_t stream) {
    const float* feat  = (const float*)d_in[0];
    const float* convw = (const float*)d_in[1];
    const float* convb = (const float*)d_in[2];
    const float* clsw  = (const float*)d_in[3];
    const float* clsb  = (const float*)d_in[4];
    const float* bboxw = (const float*)d_in[5];
    const float* bboxb = (const float*)d_in[6];
    const int*   imh   = (const int*)d_in[7];
    const int*   imw   = (const int*)d_in[8];

    if (ws_size < (size_t)WS_TOTAL * sizeof(float)) return;

    float*    scores = (float*)d_ws + WS_SCORES;
    float*    deltas = (float*)d_ws + WS_DELTAS;
    float*    boxes  = (float*)d_ws + WS_BOXES;
    unsigned* topi   = (unsigned*)((float*)d_ws + WS_TOPI);
    _Float16* whi    = (_Float16*)((float*)d_ws + WS_WHI);
    _Float16* wlo    = (_Float16*)((float*)d_ws + WS_WLO);
    float*    outp   = (float*)d_out;

    split_w<<<dim3(256), dim3(256), 0, stream>>>(convw, whi, wlo);
    conv_mfma<<<dim3(256), dim3(512), 0, stream>>>(feat, convb, whi, wlo, clsw, bboxw,
                                                   scores, deltas);
    topk_kernel<<<dim3(BB), dim3(1024), 0, stream>>>(scores, clsb, topi);
    decode_kernel<<<dim3((BB*PRE_K + 255)/256), dim3(256), 0, stream>>>(deltas, bboxb, topi, imh, imw, boxes);
    nms_kernel<<<dim3(BB), dim3(1024), 0, stream>>>(boxes, outp);
}